// Round 1
// baseline (337.798 us; speedup 1.0000x reference)
//
#include <hip/hip_runtime.h>
#include <math.h>

// BEV deformable attention encoder, layer l = L-1 only (faithful to reference).
// Pipeline: q-conv -> offset dw-conv+gelu -> offset 1x1+tanh + grid_sample ->
//           k/v conv -> CPB bias MLP (dominant) -> fused attn -> out proj.
// All fp32 this round (correctness baseline; threshold is 2% of ref absmax).

#define NP 1600   // 40*40 query pixels
#define NJ 100    // 10*10 kv pixels

// ---------------- grouped 1x1 conv: 8 groups, cin/g=32, cout/g=64 ----------
// grid 64 blocks: block b -> g = b>>3, 8 consecutive cout each. P = 1600 or 100.
__global__ __launch_bounds__(256) void k_conv1x1(
    const float* __restrict__ x, const float* __restrict__ w,
    float* __restrict__ out, int P) {
  int b = blockIdx.x;
  int g = b >> 3;
  int co0 = g * 64 + (b & 7) * 8;
  const float* xg = x + g * 32 * P;
  const float* wr = w + co0 * 32;   // uniform -> scalar loads
  for (int p = threadIdx.x; p < P; p += 256) {
    float acc[8];
#pragma unroll
    for (int o = 0; o < 8; ++o) acc[o] = 0.f;
#pragma unroll
    for (int ci = 0; ci < 32; ++ci) {
      float xv = xg[ci * P + p];
#pragma unroll
      for (int o = 0; o < 8; ++o) acc[o] = fmaf(wr[o * 32 + ci], xv, acc[o]);
    }
#pragma unroll
    for (int o = 0; o < 8; ++o) out[(co0 + o) * P + p] = acc[o];
  }
}

// ---------------- offset depthwise 6x6 stride-4 pad-1 + bias + exact GELU ---
__global__ __launch_bounds__(256) void k_off_dw(
    const float* __restrict__ q, const float* __restrict__ w1,
    const float* __restrict__ b1, float* __restrict__ off1) {
  int idx = blockIdx.x * 256 + threadIdx.x;   // 8*64*100 = 51200 exactly
  int j = idx % 100;
  int d = (idx / 100) & 63;
  int bg = idx / 6400;
  int oy = j / 10, ox = j % 10;
  float acc = b1[d];
  const float* qc = q + (bg * 64 + d) * NP;
#pragma unroll
  for (int ky = 0; ky < 6; ++ky) {
    int iy = oy * 4 - 1 + ky;
    if (iy < 0 || iy >= 40) continue;
#pragma unroll
    for (int kx = 0; kx < 6; ++kx) {
      int ix = ox * 4 - 1 + kx;
      if (ix < 0 || ix >= 40) continue;
      acc = fmaf(w1[d * 36 + ky * 6 + kx], qc[iy * 40 + ix], acc);
    }
  }
  // exact gelu: x * 0.5 * (1 + erf(x/sqrt(2)))
  off1[idx] = 0.5f * acc * (1.0f + erff(acc * 0.70710678118654752440f));
}

// ------------- offset 1x1 -> tanh*4 -> vgrid_scaled + bilinear grid_sample --
__global__ __launch_bounds__(128) void k_off_pw_sample(
    const float* __restrict__ off1, const float* __restrict__ w2,
    const float* __restrict__ x, float* __restrict__ gkv,
    float* __restrict__ kv) {
  int g = blockIdx.x;
  int j = threadIdx.x;
  if (j >= 100) return;
  float ax = 0.f, ay = 0.f;
#pragma unroll 16
  for (int c = 0; c < 64; ++c) {
    float o = off1[(g * 64 + c) * 100 + j];
    ax = fmaf(w2[c], o, ax);
    ay = fmaf(w2[64 + c], o, ay);
  }
  ax = tanhf(ax) * 4.f;
  ay = tanhf(ay) * 4.f;
  float vx = (float)(j % 10) + ax;
  float vy = (float)(j / 10) + ay;
  float g0 = 2.f * vx / 9.f - 1.f;   // normalize_grid: both axes /(10-1)
  float g1 = 2.f * vy / 9.f - 1.f;
  gkv[(g * 100 + j) * 2 + 0] = g0;
  gkv[(g * 100 + j) * 2 + 1] = g1;
  // grid_sample bilinear, zeros padding, align_corners=False, img 40x40
  float gx = ((g0 + 1.f) * 40.f - 1.f) * 0.5f;
  float gy = ((g1 + 1.f) * 40.f - 1.f) * 0.5f;
  float x0f = floorf(gx), y0f = floorf(gy);
  float wx = gx - x0f, wy = gy - y0f;
  bool mx0 = (x0f >= 0.f) && (x0f <= 39.f);
  bool mx1 = (x0f + 1.f >= 0.f) && (x0f + 1.f <= 39.f);
  bool my0 = (y0f >= 0.f) && (y0f <= 39.f);
  bool my1 = (y0f + 1.f >= 0.f) && (y0f + 1.f <= 39.f);
  int ix0 = (int)fminf(fmaxf(x0f, 0.f), 39.f);
  int ix1 = (int)fminf(fmaxf(x0f + 1.f, 0.f), 39.f);
  int iy0 = (int)fminf(fmaxf(y0f, 0.f), 39.f);
  int iy1 = (int)fminf(fmaxf(y0f + 1.f, 0.f), 39.f);
  float w00 = (1.f - wx) * (1.f - wy) * ((mx0 && my0) ? 1.f : 0.f);
  float w10 = wx * (1.f - wy) * ((mx1 && my0) ? 1.f : 0.f);
  float w01 = (1.f - wx) * wy * ((mx0 && my1) ? 1.f : 0.f);
  float w11 = wx * wy * ((mx1 && my1) ? 1.f : 0.f);
  int b00 = iy0 * 40 + ix0, b10 = iy0 * 40 + ix1;
  int b01 = iy1 * 40 + ix0, b11 = iy1 * 40 + ix1;
  const float* xg = x + g * 32 * NP;
  for (int c = 0; c < 32; ++c) {
    const float* xc = xg + c * NP;
    float val = w00 * xc[b00] + w10 * xc[b10] + w01 * xc[b01] + w11 * xc[b11];
    kv[(g * 32 + c) * 100 + j] = val;
  }
}

// ---------------- CPB bias MLP: 2 -> 64 -> relu -> 64 -> relu -> 1 ---------
// pair id p = (g*1600 + i)*100 + j ; 2 pairs per thread (2 indep FMA chains).
// Weights read wave-uniformly -> expect s_load scalarization (K$), no LDS.
__global__ __launch_bounds__(256) void k_cpb(
    const float* __restrict__ gkv,
    const float* __restrict__ w0, const float* __restrict__ b0,
    const float* __restrict__ w1, const float* __restrict__ b1v,
    const float* __restrict__ w2, const float* __restrict__ b2,
    float* __restrict__ bias) {
  int tg = blockIdx.x * 256 + threadIdx.x;   // 640000 threads exactly
  int p0 = tg * 2;
  float h0A[64], h0B[64];
  auto mk_h0 = [&](int p, float* h0) {
    int g = p / 160000;
    int r = p - g * 160000;
    int i = r / 100;
    int j = r - i * 100;
    float qx = (float)(i % 40) * (2.f / 39.f) - 1.f;
    float qy = (float)(i / 40) * (2.f / 39.f) - 1.f;
    float u = qx - gkv[(g * 100 + j) * 2 + 0];
    float vv = qy - gkv[(g * 100 + j) * 2 + 1];
    float su = copysignf(log1pf(fabsf(u)), u);
    float sv = copysignf(log1pf(fabsf(vv)), vv);
#pragma unroll
    for (int kk = 0; kk < 64; ++kk) {
      float t0 = fmaf(w0[2 * kk], su, fmaf(w0[2 * kk + 1], sv, b0[kk]));
      h0[kk] = fmaxf(t0, 0.f);
    }
  };
  mk_h0(p0, h0A);
  mk_h0(p0 + 1, h0B);
  float bA = 0.f, bB = 0.f;
  for (int c = 0; c < 64; ++c) {
    const float* wr = w1 + c * 64;
    float sA = b1v[c], sB = sA;
#pragma unroll
    for (int kk = 0; kk < 64; ++kk) {
      float wv = wr[kk];
      sA = fmaf(wv, h0A[kk], sA);
      sB = fmaf(wv, h0B[kk], sB);
    }
    float wc = w2[c];
    bA = fmaf(wc, fmaxf(sA, 0.f), bA);
    bB = fmaf(wc, fmaxf(sB, 0.f), bB);
  }
  float bb = b2[0];
  bias[p0] = bA + bb;
  bias[p0 + 1] = bB + bb;
}

// ---------------- fused attention per (head, 32-query tile) ----------------
__global__ __launch_bounds__(256) void k_attn(
    const float* __restrict__ q, const float* __restrict__ k,
    const float* __restrict__ v, const float* __restrict__ bias,
    float* __restrict__ inner) {
  __shared__ float k_lds[64][102];   // [d][j], reads at fixed d: consecutive j -> conflict-free
  __shared__ float v_lds[100][66];   // [j][d], PV reads broadcast-8
  __shared__ float q_lds[32][66];    // pad 66: 2-way on write = free
  __shared__ float s_lds[32][100];
  int h = blockIdx.x / 50;
  int i0 = (blockIdx.x % 50) * 32;
  int t = threadIdx.x;
  for (int idx = t; idx < 6400; idx += 256) {
    int d = idx / 100, j = idx % 100;         // coalesced global reads
    k_lds[d][j] = k[(h * 64 + d) * 100 + j];
    v_lds[j][d] = v[(h * 64 + d) * 100 + j];
  }
  for (int idx = t; idx < 2048; idx += 256) {
    int d = idx >> 5, i = idx & 31;
    q_lds[i][d] = q[(h * 64 + d) * NP + i0 + i] * 0.125f;  // DIM_HEAD^-0.5
  }
  __syncthreads();
  // sim = (q*scale).k + bias
  const float* brow = bias + (h * 1600 + i0) * 100;
  for (int idx = t; idx < 3200; idx += 256) {
    int i = idx / 100, j = idx % 100;
    float acc = brow[idx];
#pragma unroll
    for (int d = 0; d < 64; ++d)
      acc = fmaf(q_lds[i][d], k_lds[d][j], acc);
    s_lds[i][j] = acc;
  }
  __syncthreads();
  // softmax over j (8 lanes per row, all in-wave)
  {
    int i = t >> 3, sub = t & 7;
    float m = -1e30f;
    for (int j = sub; j < 100; j += 8) m = fmaxf(m, s_lds[i][j]);
#pragma unroll
    for (int off = 1; off < 8; off <<= 1) m = fmaxf(m, __shfl_xor(m, off));
    float sum = 0.f;
    for (int j = sub; j < 100; j += 8) {
      float e = expf(s_lds[i][j] - m);
      s_lds[i][j] = e;
      sum += e;
    }
#pragma unroll
    for (int off = 1; off < 8; off <<= 1) sum += __shfl_xor(sum, off);
    float inv = 1.f / sum;
    for (int j = sub; j < 100; j += 8) s_lds[i][j] *= inv;
  }
  __syncthreads();
  // PV: thread (i = t>>3, dc = t&7) owns d = dc, dc+8, ..., dc+56
  {
    int i = t >> 3, dc = t & 7;
    float acc[8];
#pragma unroll
    for (int dd = 0; dd < 8; ++dd) acc[dd] = 0.f;
    for (int j = 0; j < 100; ++j) {
      float a = s_lds[i][j];
#pragma unroll
      for (int dd = 0; dd < 8; ++dd)
        acc[dd] = fmaf(a, v_lds[j][dd * 8 + dc], acc[dd]);
    }
#pragma unroll
    for (int dd = 0; dd < 8; ++dd)
      inner[(h * 64 + dd * 8 + dc) * NP + i0 + i] = acc[dd];
  }
}

// ---------------- output projection 256x512 @ 512x1600 + bias --------------
__global__ __launch_bounds__(256) void k_proj(
    const float* __restrict__ inner, const float* __restrict__ w,
    const float* __restrict__ bo, float* __restrict__ out) {
  int o0 = (blockIdx.x & 63) * 4;        // 64 o-chunks
  int p0 = (blockIdx.x >> 6) * 320;      // 5 p-tiles
  const float* w0r = w + o0 * 512;       // uniform -> scalar loads
  for (int p = p0 + threadIdx.x; p < p0 + 320; p += 256) {
    float a0 = 0.f, a1 = 0.f, a2 = 0.f, a3 = 0.f;
#pragma unroll 8
    for (int c = 0; c < 512; ++c) {
      float xv = inner[c * NP + p];
      a0 = fmaf(w0r[c], xv, a0);
      a1 = fmaf(w0r[512 + c], xv, a1);
      a2 = fmaf(w0r[1024 + c], xv, a2);
      a3 = fmaf(w0r[1536 + c], xv, a3);
    }
    out[(o0 + 0) * NP + p] = a0 + bo[o0 + 0];
    out[(o0 + 1) * NP + p] = a1 + bo[o0 + 1];
    out[(o0 + 2) * NP + p] = a2 + bo[o0 + 2];
    out[(o0 + 3) * NP + p] = a3 + bo[o0 + 3];
  }
}

extern "C" void kernel_launch(void* const* d_in, const int* in_sizes, int n_in,
                              void* d_out, int out_size, void* d_ws, size_t ws_size,
                              hipStream_t stream) {
  // number of layers from wq flat size (L*512*32); we need the LAST layer only.
  int L = in_sizes[1] / (512 * 32);
  int l = L - 1;
  const float* x      = (const float*)d_in[0];
  const float* wq     = (const float*)d_in[1]  + (size_t)l * 512 * 32;
  const float* wk     = (const float*)d_in[2]  + (size_t)l * 512 * 32;
  const float* wv     = (const float*)d_in[3]  + (size_t)l * 512 * 32;
  const float* w_off1 = (const float*)d_in[4]  + (size_t)l * 64 * 36;
  const float* b_off1 = (const float*)d_in[5]  + (size_t)l * 64;
  const float* w_off2 = (const float*)d_in[6]  + (size_t)l * 2 * 64;
  const float* cpb_w0 = (const float*)d_in[7]  + (size_t)l * 64 * 2;
  const float* cpb_b0 = (const float*)d_in[8]  + (size_t)l * 64;
  const float* cpb_w1 = (const float*)d_in[9]  + (size_t)l * 64 * 64;
  const float* cpb_b1 = (const float*)d_in[10] + (size_t)l * 64;
  const float* cpb_w2 = (const float*)d_in[11] + (size_t)l * 64;
  const float* cpb_b2 = (const float*)d_in[12] + (size_t)l * 1;
  const float* w_out  = (const float*)d_in[13] + (size_t)l * 256 * 512;
  const float* b_out  = (const float*)d_in[14] + (size_t)l * 256;
  float* out = (float*)d_out;

  float* ws = (float*)d_ws;
  float* q_ws    = ws;               // 512*1600      = 819200
  float* off1    = ws + 819200;      // 8*64*100      = 51200
  float* gkv     = ws + 870400;      // 8*100*2       = 1600
  float* kv      = ws + 872000;      // 256*100       = 25600
  float* k_ws    = ws + 897600;      // 512*100       = 51200
  float* v_ws    = ws + 948800;      // 512*100       = 51200
  float* bias_ws = ws + 1000000;     // 8*1600*100    = 1280000
  float* inner   = ws + 2280000;     // 512*1600      = 819200
  // total 3,099,200 floats = 12.4 MB

  k_conv1x1<<<64, 256, 0, stream>>>(x, wq, q_ws, NP);
  k_off_dw<<<200, 256, 0, stream>>>(q_ws, w_off1, b_off1, off1);
  k_off_pw_sample<<<8, 128, 0, stream>>>(off1, w_off2, x, gkv, kv);
  k_conv1x1<<<64, 256, 0, stream>>>(kv, wk, k_ws, NJ);
  k_conv1x1<<<64, 256, 0, stream>>>(kv, wv, v_ws, NJ);
  k_cpb<<<2500, 256, 0, stream>>>(gkv, cpb_w0, cpb_b0, cpb_w1, cpb_b1,
                                  cpb_w2, cpb_b2, bias_ws);
  k_attn<<<400, 256, 0, stream>>>(q_ws, k_ws, v_ws, bias_ws, inner);
  k_proj<<<320, 256, 0, stream>>>(inner, w_out, b_out, out);
}